// Round 13
// baseline (282.688 us; speedup 1.0000x reference)
//
#include <hip/hip_runtime.h>
#include <hip/hip_fp16.h>

// GCN forward: 3x (GCNConv improved + ReLU) + GCNConv(out, 1 feature)
// N=50000, E=1.6M, H=64.
// R12 conclusion: agg floor = random 64B line-fill service (~1.2 TB/s) x
// 8-XCD compulsory duplication of the 6.4MB table (51MB/layer). This round:
// 4-way src-slice partition. Sort key = slice*n+dst -> 4 per-slice CSRs.
// k_scat: class c=(blockIdx&7)>>1 (XCD-pair heuristic) gathers ONLY its
// 1.6MB slice (L2-resident) -> fp16 partial sums (streaming NT writes).
// k_reduce: sum 4 partials + self + bias + relu (pure streaming).
// Random fills 51 -> 12.8 MB/layer; rest is streaming at ~5 TB/s.
// Correctness does NOT depend on the XCD mapping (classes = deterministic
// work split); only speed does.

#define HF 64
#define EPB 16384         // edges per block in passes A/B  (G = ceil(E/EPB))

// ---------------- pass A: coarse histogram (bucket = key>>10) ----------------
// key = slice(src)*n + dst, slice = src/q (q = ceil(n/4)), key < 4n = 200000
__global__ __launch_bounds__(256) void pA_hist(const int* __restrict__ src,
                                               const int* __restrict__ dst,
                                               int* __restrict__ histT,
                                               int E, int G, int n, int q) {
    __shared__ int h[256];
    int g = blockIdx.x, t = threadIdx.x;
    h[t] = 0;
    __syncthreads();
    int beg = g * EPB, end = min(beg + EPB, E);
    for (int i = beg + t; i < end; i += 256) {
        int s = src[i], d = dst[i];
        int slice = (s >= 3 * q) ? 3 : (s >= 2 * q) ? 2 : (s >= q) ? 1 : 0;
        int key = slice * n + d;
        atomicAdd(&h[key >> 10], 1);
    }
    __syncthreads();
    histT[t * G + g] = h[t];
}

// ---- scan level 1: 256 blocks, bucket b scans its G entries ----
__global__ __launch_bounds__(128) void pScan1(int* __restrict__ hist,
                                              int* __restrict__ bsum, int G) {
    __shared__ int sd[128];
    int b = blockIdx.x, t = threadIdx.x;
    int runsum = 0;
    for (int base = 0; base < G; base += 128) {
        int idx = base + t;
        int v = (idx < G) ? hist[b * G + idx] : 0;
        sd[t] = v;
        __syncthreads();
        for (int o = 1; o < 128; o <<= 1) {
            int u = (t >= o) ? sd[t - o] : 0;
            __syncthreads();
            sd[t] += u;
            __syncthreads();
        }
        if (idx < G) hist[b * G + idx] = runsum + sd[t] - v;  // exclusive
        runsum += sd[127];
        __syncthreads();
    }
    if (t == 0) bsum[b] = runsum;
}

// ---- scan level 2: one block scans the 256 bucket totals -> coarse ----
__global__ __launch_bounds__(256) void pScan2(const int* __restrict__ bsum,
                                              int* __restrict__ coarse, int E) {
    __shared__ int sd[256];
    int t = threadIdx.x;
    int v = bsum[t];
    sd[t] = v;
    __syncthreads();
    for (int o = 1; o < 256; o <<= 1) {
        int u = (t >= o) ? sd[t - o] : 0;
        __syncthreads();
        sd[t] += u;
        __syncthreads();
    }
    coarse[t] = sd[t] - v;
    if (t == 255) coarse[256] = E;
}

// ---------------- pass B: coarse scatter (LDS cursors) ----------------
__global__ __launch_bounds__(256) void pB_scatter(const int* __restrict__ src,
                                                  const int* __restrict__ dst,
                                                  const int* __restrict__ histT,
                                                  const int* __restrict__ coarse,
                                                  unsigned int* __restrict__ tmp,
                                                  int E, int G, int n, int q) {
    __shared__ int cur[256];
    int g = blockIdx.x, t = threadIdx.x;
    cur[t] = coarse[t] + histT[t * G + g];
    __syncthreads();
    int beg = g * EPB, end = min(beg + EPB, E);
    for (int i = beg + t; i < end; i += 256) {
        int s = src[i], d = dst[i];
        int slice = (s >= 3 * q) ? 3 : (s >= 2 * q) ? 2 : (s >= q) ? 1 : 0;
        int key = slice * n + d;
        int pos = atomicAdd(&cur[key >> 10], 1);
        tmp[pos] = ((unsigned int)(key & 1023) << 16) | (unsigned int)(s & 0xFFFF);
    }
}

// ------ pass C: per-bucket fine counting sort (1024 bins) + offs4 ------------
__global__ __launch_bounds__(256) void pC_build(const unsigned int* __restrict__ tmp,
                                                const int* __restrict__ coarse,
                                                ushort* __restrict__ csrs,
                                                int* __restrict__ offs4,
                                                int n4, int E, int NB2) {
    __shared__ int hist[1024];
    __shared__ int cur[1024];
    __shared__ int tsum[256];
    int b = blockIdx.x, t = threadIdx.x;
    int beg = coarse[b], end = coarse[b + 1];
#pragma unroll
    for (int j = 0; j < 4; ++j) hist[4 * t + j] = 0;
    __syncthreads();
    for (int i = beg + t; i < end; i += 256) atomicAdd(&hist[tmp[i] >> 16], 1);
    __syncthreads();
    int h0 = hist[4 * t], h1 = hist[4 * t + 1], h2 = hist[4 * t + 2], h3 = hist[4 * t + 3];
    int s = h0 + h1 + h2 + h3;
    tsum[t] = s;
    __syncthreads();
    for (int o = 1; o < 256; o <<= 1) {
        int u = (t >= o) ? tsum[t - o] : 0;
        __syncthreads();
        tsum[t] += u;
        __syncthreads();
    }
    int b0 = beg + tsum[t] - s;          // exclusive start of this thread's 4 bins
    cur[4 * t + 0] = b0;
    cur[4 * t + 1] = b0 + h0;
    cur[4 * t + 2] = b0 + h0 + h1;
    cur[4 * t + 3] = b0 + h0 + h1 + h2;
    int keybase = (b << 10) + 4 * t;
#pragma unroll
    for (int j = 0; j < 4; ++j) {
        int key = keybase + j;
        if (key < n4) offs4[key] = cur[4 * t + j];
    }
    if (b == NB2 - 1 && t == 0) offs4[n4] = E;
    __syncthreads();
    for (int i = beg + t; i < end; i += 256) {
        unsigned int e = tmp[i];
        int pos = atomicAdd(&cur[e >> 16], 1);
        csrs[pos] = (ushort)(e & 0xFFFFu);
    }
}

// ---- degree norms from offs4 (cumulative offsets -> per-slice counts sum) ----
__global__ void k_dis(const int* __restrict__ offs4, float* __restrict__ di,
                      float* __restrict__ dp, int n) {
    int i = blockIdx.x * blockDim.x + threadIdx.x;
    if (i < n) {
        int deg = 0;
#pragma unroll
        for (int s = 0; s < 4; ++s)
            deg += offs4[(size_t)s * n + i + 1] - offs4[(size_t)s * n + i];
        float df = (float)deg;
        di[i] = rsqrtf(df + 2.0f);   // improved=True: self-loop weight 2
        dp[i] = rsqrtf(df + 1.0f);   // output layer: improved=False
    }
}

// ---- dense GEMM: C[n,64] = di[n] * (A[n,64] @ W[64,64]), C in fp16 ----------
#define GM_BN 128
__global__ __launch_bounds__(256) void k_gemm(const float* __restrict__ A,
                                              const float* __restrict__ W,
                                              const float* __restrict__ di,
                                              __half* __restrict__ C, int n) {
    __shared__ float xT[64][132];
    __shared__ float Wl[64][64];
    int tid = threadIdx.x;
    int nb = blockIdx.x * GM_BN;

    for (int r = 0; r < 4; ++r) {
        int q = tid + 256 * r;
        int row = q >> 4, c4 = (q & 15) << 2;
        *(float4*)&Wl[row][c4] = *(const float4*)&W[row * 64 + c4];
    }
    for (int r = 0; r < 8; ++r) {
        int q = tid + 256 * r;
        int nl = q >> 4, k0 = (q & 15) << 2;
        float4 v = make_float4(0.f, 0.f, 0.f, 0.f);
        if (nb + nl < n) v = *(const float4*)&A[(size_t)(nb + nl) * HF + k0];
        xT[k0 + 0][nl] = v.x; xT[k0 + 1][nl] = v.y;
        xT[k0 + 2][nl] = v.z; xT[k0 + 3][nl] = v.w;
    }
    __syncthreads();

    int tx = tid & 7;
    int ty = tid >> 3;
    int f0 = tx * 8, n0 = ty * 4;
    float acc[4][8];
#pragma unroll
    for (int i = 0; i < 4; ++i)
#pragma unroll
        for (int j = 0; j < 8; ++j) acc[i][j] = 0.f;

#pragma unroll 4
    for (int k = 0; k < 64; ++k) {
        float4 xa = *(float4*)&xT[k][n0];
        float4 wa = *(float4*)&Wl[k][f0];
        float4 wb = *(float4*)&Wl[k][f0 + 4];
        float xs[4] = {xa.x, xa.y, xa.z, xa.w};
        float wsv[8] = {wa.x, wa.y, wa.z, wa.w, wb.x, wb.y, wb.z, wb.w};
#pragma unroll
        for (int i = 0; i < 4; ++i)
#pragma unroll
            for (int j = 0; j < 8; ++j) acc[i][j] += xs[i] * wsv[j];
    }

#pragma unroll
    for (int i = 0; i < 4; ++i) {
        int nn = nb + n0 + i;
        if (nn < n) {
            float dr = di[nn];                  // fold edge weight into table
            union { __half h[8]; float4 f4; } u;
#pragma unroll
            for (int j = 0; j < 8; ++j) u.h[j] = __float2half(acc[i][j] * dr);
            *(float4*)&C[(size_t)nn * HF + f0] = u.f4;
        }
    }
}

// ---- phase 1: class-partitioned scatter. class c = (blockIdx&7)>>1 ----------
// Each class gathers only slice c (1.6MB, L2-resident on its XCD pair) and
// writes fp16 partial edge-sums for ALL nodes.
__global__ __launch_bounds__(256) void k_scat(const __half2* __restrict__ P2,
                                              const int* __restrict__ offs4,
                                              const ushort* __restrict__ csrs,
                                              __half2* __restrict__ part, int n) {
    int bid = blockIdx.x;
    int c = (bid & 7) >> 1;
    int rank = ((bid >> 3) << 1) | (bid & 1);       // 0..511 within class
    int wrank = rank * 4 + (threadIdx.x >> 6);      // 0..2047 within class
    int lane = threadIdx.x & 63;
    int half = lane >> 5, fh = lane & 31;
    const int* offc = offs4 + (size_t)c * n;
    __half2* pc = part + (size_t)c * n * 32;
    for (int node = wrank; node < n; node += 2048) {
        int beg = offc[node], deg = offc[node + 1] - beg;
        float a0 = 0.f, a1 = 0.f;
        int pairs = deg >> 1;
        int e = beg + half;
        int c2 = pairs >> 1;
        for (int i2 = 0; i2 < c2; ++i2, e += 4) {
            int s0 = csrs[e], s1 = csrs[e + 2];
            float2 v0 = __half22float2(P2[(size_t)s0 * 32 + fh]);
            float2 v1 = __half22float2(P2[(size_t)s1 * 32 + fh]);
            a0 += v0.x; a1 += v0.y;
            a0 += v1.x; a1 += v1.y;
        }
        if (pairs & 1) {
            int s0 = csrs[e];
            float2 v = __half22float2(P2[(size_t)s0 * 32 + fh]);
            a0 += v.x; a1 += v.y;
        }
        if ((deg & 1) && half == 0) {
            int s0 = csrs[beg + deg - 1];
            float2 v = __half22float2(P2[(size_t)s0 * 32 + fh]);
            a0 += v.x; a1 += v.y;
        }
        a0 += __shfl_xor(a0, 32);
        a1 += __shfl_xor(a1, 32);
        if (half == 0) {
            __half2 hv = __floats2half2_rn(a0, a1);
            unsigned uv = *(unsigned*)&hv;
            __builtin_nontemporal_store(uv, (unsigned*)(pc + (size_t)node * 32 + fh));
        }
    }
}

// ---- phase 2: reduce 4 partials + self + bias + relu (pure streaming) -------
__global__ __launch_bounds__(256) void k_reduce(const __half2* __restrict__ part,
                                                const __half2* __restrict__ P2,
                                                const float* __restrict__ di,
                                                const float* __restrict__ bias,
                                                float* __restrict__ out, int n,
                                                float fill) {
    int idx = blockIdx.x * 256 + threadIdx.x;
    int node = idx >> 5, fh = idx & 31;
    if (node >= n) return;
    float a0 = 0.f, a1 = 0.f;
#pragma unroll
    for (int s = 0; s < 4; ++s) {
        float2 v = __half22float2(part[((size_t)s * n + node) * 32 + fh]);
        a0 += v.x; a1 += v.y;
    }
    float dw = di[node];
    float2 self = __half22float2(P2[(size_t)node * 32 + fh]);
    float h0 = fmaxf(dw * (a0 + fill * self.x) + bias[2 * fh + 0], 0.f);
    float h1 = fmaxf(dw * (a1 + fill * self.y) + bias[2 * fh + 1], 0.f);
    float* op = &out[(size_t)node * HF + 2 * fh];
    __builtin_nontemporal_store(h0, op);
    __builtin_nontemporal_store(h1, op + 1);
}

// ---- phase 2 for layer 3: reduce fused with output projection -> z2 ---------
__global__ __launch_bounds__(256) void k_reduce_final(const __half2* __restrict__ part,
                                                      const __half2* __restrict__ P2,
                                                      const float* __restrict__ di,
                                                      const float* __restrict__ bias,
                                                      const float* __restrict__ Wout,
                                                      const float* __restrict__ dp,
                                                      float* __restrict__ z2, int n) {
    int idx = blockIdx.x * 256 + threadIdx.x;
    int node = idx >> 5, fh = idx & 31;
    if (node >= n) return;
    float a0 = 0.f, a1 = 0.f;
#pragma unroll
    for (int s = 0; s < 4; ++s) {
        float2 v = __half22float2(part[((size_t)s * n + node) * 32 + fh]);
        a0 += v.x; a1 += v.y;
    }
    float dw = di[node];
    float2 self = __half22float2(P2[(size_t)node * 32 + fh]);
    float h0 = fmaxf(dw * (a0 + 2.0f * self.x) + bias[2 * fh + 0], 0.f);
    float h1 = fmaxf(dw * (a1 + 2.0f * self.y) + bias[2 * fh + 1], 0.f);
    float v = h0 * Wout[2 * fh] + h1 * Wout[2 * fh + 1];
#pragma unroll
    for (int o = 16; o > 0; o >>= 1) v += __shfl_down(v, o, 32);
    if ((threadIdx.x & 31) == 0) z2[node] = v * dp[node];
}

// out[n] = dp[n]*(sum_e z2[src] + z2[n]) + b_out  (16 lanes/node, 4 segments)
__global__ __launch_bounds__(256) void k_out(const float* __restrict__ z2,
                      const int* __restrict__ offs4, const ushort* __restrict__ csrs,
                      const float* __restrict__ dp, const float* __restrict__ bout,
                      float* __restrict__ out, int n) {
    int node = (blockIdx.x * blockDim.x + threadIdx.x) >> 4;
    if (node >= n) return;
    int l = threadIdx.x & 15;
    float acc = 0.f;
#pragma unroll
    for (int s = 0; s < 4; ++s) {
        int beg = offs4[(size_t)s * n + node], end = offs4[(size_t)s * n + node + 1];
        for (int e = beg + l; e < end; e += 16) acc += z2[csrs[e]];
    }
#pragma unroll
    for (int o = 8; o > 0; o >>= 1) acc += __shfl_down(acc, o, 16);
    if (l == 0) out[node] = dp[node] * (acc + z2[node]) + bout[0];
}

extern "C" void kernel_launch(void* const* d_in, const int* in_sizes, int n_in,
                              void* d_out, int out_size, void* d_ws, size_t ws_size,
                              hipStream_t stream) {
    const float* x    = (const float*)d_in[0];
    const int*   ei   = (const int*)d_in[1];
    const float* W_in = (const float*)d_in[2];
    const float* b_in = (const float*)d_in[3];
    const float* W_h1 = (const float*)d_in[4];
    const float* b_h1 = (const float*)d_in[5];
    const float* W_h2 = (const float*)d_in[6];
    const float* b_h2 = (const float*)d_in[7];
    const float* W_out= (const float*)d_in[8];
    const float* b_out= (const float*)d_in[9];
    float* out = (float*)d_out;

    const int n = in_sizes[0] / HF;        // 50000 (< 65536: ushort CSR ok)
    const int E = in_sizes[1] / 2;         // 1.6M
    const int* src = ei;
    const int* dst = ei + E;

    const int q   = (n + 3) >> 2;          // slice size (12500)
    const int n4  = 4 * n;                 // key space
    const int G   = (E + EPB - 1) / EPB;   // 98
    const int NB2 = (n4 + 1023) >> 10;     // fine-sort blocks (196)

    char* ws = (char*)d_ws;
    size_t o = 0;
    auto alloc = [&](size_t bytes) -> void* {
        void* p = ws + o;
        o += (bytes + 255) & ~(size_t)255;
        return p;
    };
    int*          offs4  = (int*)   alloc((size_t)(n4 + 1) * 4);
    float*        di     = (float*) alloc((size_t)n * 4);
    float*        dp     = (float*) alloc((size_t)n * 4);
    ushort*       csrs   = (ushort*)alloc((size_t)E * 2);
    unsigned int* tmp    = (unsigned int*)alloc((size_t)E * 4);
    int*          histT  = (int*)   alloc((size_t)G * 256 * 4);
    int*          bsum   = (int*)   alloc(256 * 4);
    int*          coarse = (int*)   alloc(257 * 4);
    __half*       hW     = (__half*)alloc((size_t)n * HF * 2);       // fp16 P' table
    __half2*      part   = (__half2*)alloc((size_t)4 * n * 32 * 4);  // 4 partial bufs
    float*        hA     = (float*) alloc((size_t)n * HF * 4);
    float*        hB     = (float*) alloc((size_t)n * HF * 4);
    float*        z2     = (float*) alloc((size_t)n * 4);

    const int TB = 256;
    int gbDis = (n + TB - 1) / TB;
    int gbR   = (n * 32 + TB - 1) / TB;
    int gbO   = (n * 16 + TB - 1) / TB;
    int gbG   = (n + GM_BN - 1) / GM_BN;

    // ---- CSR build: 4 per-slice CSRs via (slice,dst) counting sort ----
    pA_hist   <<<G,   TB, 0, stream>>>(src, dst, histT, E, G, n, q);
    pScan1    <<<256, 128, 0, stream>>>(histT, bsum, G);
    pScan2    <<<1,   TB, 0, stream>>>(bsum, coarse, E);
    pB_scatter<<<G,   TB, 0, stream>>>(src, dst, histT, coarse, tmp, E, G, n, q);
    pC_build  <<<NB2, TB, 0, stream>>>(tmp, coarse, csrs, offs4, n4, E, NB2);
    k_dis     <<<gbDis, TB, 0, stream>>>(offs4, di, dp, n);

    const __half2* hW2 = (const __half2*)hW;

    // ---- layer 1 ----
    k_gemm  <<<gbG,  TB, 0, stream>>>(x, W_in, di, hW, n);
    k_scat  <<<2048, TB, 0, stream>>>(hW2, offs4, csrs, part, n);
    k_reduce<<<gbR,  TB, 0, stream>>>(part, hW2, di, b_in, hA, n, 2.0f);
    // ---- layer 2 ----
    k_gemm  <<<gbG,  TB, 0, stream>>>(hA, W_h1, di, hW, n);
    k_scat  <<<2048, TB, 0, stream>>>(hW2, offs4, csrs, part, n);
    k_reduce<<<gbR,  TB, 0, stream>>>(part, hW2, di, b_h1, hB, n, 2.0f);
    // ---- layer 3 (reduce fused with output projection) ----
    k_gemm        <<<gbG,  TB, 0, stream>>>(hB, W_h2, di, hW, n);
    k_scat        <<<2048, TB, 0, stream>>>(hW2, offs4, csrs, part, n);
    k_reduce_final<<<gbR,  TB, 0, stream>>>(part, hW2, di, b_h2, W_out, dp, z2, n);
    // ---- output layer ----
    k_out<<<gbO, TB, 0, stream>>>(z2, offs4, csrs, dp, b_out, out, n);
}